// Round 1
// baseline (1651.793 us; speedup 1.0000x reference)
//
#include <hip/hip_runtime.h>
#include <stdint.h>

// ---------------------------------------------------------------------------
// Types / helpers
// ---------------------------------------------------------------------------
typedef float  f32x4  __attribute__((ext_vector_type(4)));
typedef __bf16 bf16x8 __attribute__((ext_vector_type(8)));
typedef short  s16x8  __attribute__((ext_vector_type(8)));

#define DEV __device__ __forceinline__

DEV short f2b(float f) {  // fp32 -> bf16 bits, round-to-nearest-even
    union { float f; unsigned u; } c; c.f = f;
    unsigned u = c.u;
    unsigned r = (u + 0x7fffu + ((u >> 16) & 1u)) >> 16;
    return (short)r;
}
DEV float b2f(short s) {
    union { unsigned u; float f; } c; c.u = ((unsigned)(unsigned short)s) << 16;
    return c.f;
}

DEV void gload_lds16(const void* g, void* l) {
    // async global->LDS, 16B per lane; LDS dest = wave-uniform base + lane*16
    __builtin_amdgcn_global_load_lds(
        (const __attribute__((address_space(1))) void*)g,
        (__attribute__((address_space(3))) void*)l, 16, 0, 0);
}

// ---------------------------------------------------------------------------
// GEMM: C = A(bf16,[M,K]) * B(bf16, stored as B^T [N,K]) with fused epilogues.
// BK=64, 4 waves (2x2), wave tile (BM/2 x BN/2), mfma_f32_16x16x32_bf16.
// LDS is XOR-swizzled (seg' = seg ^ (row&7)) via pre-swizzled GLOBAL source
// (global_load_lds writes linearly), read back with the same involution ->
// ds_read_b128 is 2-way conflict (free).
// MODE 0: out bf16 (batched, stride sO)                      [QK^T scores]
// MODE 1: +bias, scatter q(*0.125)/k/v to [B,H,N,64] bf16    [QKV]
// MODE 2: +bias, exact GELU, out bf16 row-major              [FFN1]
// MODE 3: +bias, outf += (residual accumulate, fp32)         [FFN2]
// MODE 4: outf[(b*512+m)*768 + h*64 + col] += val            [PV -> x]
// ---------------------------------------------------------------------------
template<int BM, int BN, int MODE>
__global__ __launch_bounds__(256) void gemm_bt(
    const short* __restrict__ A, const short* __restrict__ Bt,
    const float* __restrict__ bias,
    float* __restrict__ outf, short* __restrict__ outs0,
    short* __restrict__ outs1, short* __restrict__ outs2,
    long sA, long sB, long sO, int M, int N, int K)
{
    constexpr int BK = 64;
    constexpr int FM = BM / 32, FN = BN / 32;
    __shared__ short As[BM * BK];
    __shared__ short Bs[BN * BK];

    const int tid  = threadIdx.x;
    const int w    = tid >> 6, lane = tid & 63;
    const int wr   = w >> 1,  wc   = w & 1;
    const int l16  = lane & 15, lhi = lane >> 4, sw = lane & 7;
    const int z    = blockIdx.z;

    const short* Ab = A  + (long)z * sA + (long)blockIdx.y * BM * K;
    const short* Bb = Bt + (long)z * sB + (long)blockIdx.x * BN * K;

    f32x4 acc[FM][FN];
#pragma unroll
    for (int m = 0; m < FM; ++m)
#pragma unroll
        for (int n = 0; n < FN; ++n) acc[m][n] = (f32x4)(0.0f);

    const int kTiles = K >> 6;
    for (int kt = 0; kt < kTiles; ++kt) {
        const short* Ag = Ab + kt * BK;
#pragma unroll
        for (int i = 0; i < BM / 32; ++i) {
            int seg = i * 256 + tid;
            int row = seg >> 3;
            int gcs = (tid & 7) ^ (row & 7);            // pre-swizzled source seg
            gload_lds16(Ag + (long)row * K + gcs * 8, As + (i * 256 + w * 64) * 8);
        }
        const short* Bg = Bb + kt * BK;
#pragma unroll
        for (int i = 0; i < BN / 32; ++i) {
            int seg = i * 256 + tid;
            int row = seg >> 3;
            int gcs = (tid & 7) ^ (row & 7);
            gload_lds16(Bg + (long)row * K + gcs * 8, Bs + (i * 256 + w * 64) * 8);
        }
        __syncthreads();
#pragma unroll
        for (int kk = 0; kk < 2; ++kk) {
            bf16x8 af[FM], bfr[FN];
#pragma unroll
            for (int m = 0; m < FM; ++m) {
                int ar = wr * (BM / 2) + m * 16 + l16;
                int ks = (kk * 4 + lhi) ^ sw;           // ar&7 == sw
                af[m] = *(const bf16x8*)(As + ar * BK + ks * 8);
            }
#pragma unroll
            for (int n = 0; n < FN; ++n) {
                int br = wc * (BN / 2) + n * 16 + l16;
                int ks = (kk * 4 + lhi) ^ sw;
                bfr[n] = *(const bf16x8*)(Bs + br * BK + ks * 8);
            }
#pragma unroll
            for (int m = 0; m < FM; ++m)
#pragma unroll
                for (int n = 0; n < FN; ++n)
                    acc[m][n] = __builtin_amdgcn_mfma_f32_16x16x32_bf16(
                        af[m], bfr[n], acc[m][n], 0, 0, 0);
        }
        __syncthreads();
    }

    // Epilogue. C/D frag mapping: col = lane&15, row = (lane>>4)*4 + reg.
    const int m0 = blockIdx.y * BM, n0 = blockIdx.x * BN;
    const int zb = z / 12, zh = z - (z / 12) * 12;      // for MODE 4
#pragma unroll
    for (int m = 0; m < FM; ++m) {
#pragma unroll
        for (int n = 0; n < FN; ++n) {
            const int grow0 = m0 + wr * (BM / 2) + m * 16 + lhi * 4;
            const int gcol  = n0 + wc * (BN / 2) + n * 16 + l16;
#pragma unroll
            for (int r = 0; r < 4; ++r) {
                float val = acc[m][n][r];
                int grow = grow0 + r;
                if constexpr (MODE == 0) {
                    outs0[(long)z * sO + (long)grow * N + gcol] = f2b(val);
                } else if constexpr (MODE == 1) {
                    float v = val + bias[gcol];
                    int d  = gcol & 63;
                    int hh = gcol >> 6;                 // 0..35
                    int bb = grow >> 9, s = grow & 511;
                    if (gcol < 768) {
                        outs0[((long)((bb * 12 + hh) * 512 + s) << 6) + d] = f2b(v * 0.125f);
                    } else if (gcol < 1536) {
                        outs1[((long)((bb * 12 + (hh - 12)) * 512 + s) << 6) + d] = f2b(v);
                    } else {
                        outs2[((long)((bb * 12 + (hh - 24)) * 512 + s) << 6) + d] = f2b(v);
                    }
                } else if constexpr (MODE == 2) {
                    float v = val + bias[gcol];
                    v = 0.5f * v * (1.0f + erff(v * 0.70710678118f));
                    outs0[(long)grow * N + gcol] = f2b(v);
                } else if constexpr (MODE == 3) {
                    long idx = (long)grow * N + gcol;
                    outf[idx] += val + bias[gcol];
                } else {                                 // MODE 4
                    long idx = ((long)(zb * 512 + grow)) * 768 + zh * 64 + gcol;
                    outf[idx] += val;
                }
            }
        }
    }
}

// ---------------------------------------------------------------------------
// LayerNorm: one wave per row (768 fp32), write bf16
// ---------------------------------------------------------------------------
__global__ __launch_bounds__(256) void ln_kernel(
    const float* __restrict__ x, const float* __restrict__ g,
    const float* __restrict__ be, short* __restrict__ out)
{
    int row  = blockIdx.x * 4 + (threadIdx.x >> 6);
    int lane = threadIdx.x & 63;
    const float4* xr = (const float4*)(x + (long)row * 768);
    float4 v0 = xr[lane], v1 = xr[lane + 64], v2 = xr[lane + 128];
    float f[12] = {v0.x, v0.y, v0.z, v0.w, v1.x, v1.y, v1.z, v1.w, v2.x, v2.y, v2.z, v2.w};

    float s = 0.f;
#pragma unroll
    for (int j = 0; j < 12; ++j) s += f[j];
#pragma unroll
    for (int o = 32; o; o >>= 1) s += __shfl_xor(s, o);
    float mu = s * (1.0f / 768.0f);
    float s2 = 0.f;
#pragma unroll
    for (int j = 0; j < 12; ++j) { f[j] -= mu; s2 += f[j] * f[j]; }
#pragma unroll
    for (int o = 32; o; o >>= 1) s2 += __shfl_xor(s2, o);
    float rstd = rsqrtf(s2 * (1.0f / 768.0f) + 1e-5f);

    const float4* gr = (const float4*)g;
    const float4* br = (const float4*)be;
    short4* orow = (short4*)(out + (long)row * 768);
#pragma unroll
    for (int jb = 0; jb < 3; ++jb) {
        float4 gg = gr[lane + 64 * jb], bb = br[lane + 64 * jb];
        short4 o4;
        o4.x = f2b(f[4 * jb + 0] * rstd * gg.x + bb.x);
        o4.y = f2b(f[4 * jb + 1] * rstd * gg.y + bb.y);
        o4.z = f2b(f[4 * jb + 2] * rstd * gg.z + bb.z);
        o4.w = f2b(f[4 * jb + 3] * rstd * gg.w + bb.w);
        orow[lane + 64 * jb] = o4;
    }
}

// ---------------------------------------------------------------------------
// Softmax over rows of S (bf16 [48*512, 512]), in place. One wave per row.
// ---------------------------------------------------------------------------
__global__ __launch_bounds__(256) void softmax_kernel(short* __restrict__ SP)
{
    long row = (long)blockIdx.x * 4 + (threadIdx.x >> 6);
    int lane = threadIdx.x & 63;
    s16x8* p = (s16x8*)(SP + row * 512) + lane;
    s16x8 sv = *p;
    float f[8];
#pragma unroll
    for (int j = 0; j < 8; ++j) f[j] = b2f(sv[j]);
    float mx = f[0];
#pragma unroll
    for (int j = 1; j < 8; ++j) mx = fmaxf(mx, f[j]);
#pragma unroll
    for (int o = 32; o; o >>= 1) mx = fmaxf(mx, __shfl_xor(mx, o));
    float s = 0.f;
#pragma unroll
    for (int j = 0; j < 8; ++j) { f[j] = __expf(f[j] - mx); s += f[j]; }
#pragma unroll
    for (int o = 32; o; o >>= 1) s += __shfl_xor(s, o);
    float inv = 1.0f / s;
#pragma unroll
    for (int j = 0; j < 8; ++j) sv[j] = f2b(f[j] * inv);
    *p = sv;
}

// ---------------------------------------------------------------------------
// Weight transpose fp32[R,C] -> bf16[C,R] (tiled, coalesced both sides)
// ---------------------------------------------------------------------------
__global__ __launch_bounds__(256) void transpose_w(
    const float* __restrict__ in, short* __restrict__ out, int R, int C)
{
    __shared__ float t[32][33];
    int r0 = blockIdx.y * 32, c0 = blockIdx.x * 32;
    int tx = threadIdx.x & 31, ty = threadIdx.x >> 5;
#pragma unroll
    for (int p = 0; p < 4; ++p)
        t[ty + 8 * p][tx] = in[(long)(r0 + ty + 8 * p) * C + c0 + tx];
    __syncthreads();
#pragma unroll
    for (int p = 0; p < 4; ++p)
        out[(long)(c0 + ty + 8 * p) * R + r0 + tx] = f2b(t[tx][ty + 8 * p]);
}

// bf16 [z][R,C] -> [z][C,R] (for V -> V^T per (b,h))
__global__ __launch_bounds__(256) void transpose_v(
    const short* __restrict__ in, short* __restrict__ out, int R, int C)
{
    __shared__ short t[32][33];
    long zo = (long)blockIdx.z * R * C;
    int r0 = blockIdx.y * 32, c0 = blockIdx.x * 32;
    int tx = threadIdx.x & 31, ty = threadIdx.x >> 5;
#pragma unroll
    for (int p = 0; p < 4; ++p)
        t[ty + 8 * p][tx] = in[zo + (long)(r0 + ty + 8 * p) * C + c0 + tx];
    __syncthreads();
#pragma unroll
    for (int p = 0; p < 4; ++p)
        out[zo + (long)(c0 + ty + 8 * p) * R + r0 + tx] = t[tx][ty + 8 * p];
}

__global__ void concat_bias(const float* __restrict__ bq, const float* __restrict__ bk,
                            const float* __restrict__ bv, float* __restrict__ o)
{
    int i = blockIdx.x * 256 + threadIdx.x;
    if (i < 768) { o[i] = bq[i]; o[768 + i] = bk[i]; o[1536 + i] = bv[i]; }
}

// ---------------------------------------------------------------------------
// Host launcher
// ---------------------------------------------------------------------------
extern "C" void kernel_launch(void* const* d_in, const int* in_sizes, int n_in,
                              void* d_out, int out_size, void* d_ws, size_t ws_size,
                              hipStream_t stream)
{
    (void)in_sizes; (void)n_in; (void)out_size; (void)ws_size;
    const float* x_in = (const float*)d_in[0];
    const float* Wq  = (const float*)d_in[1];
    const float* bq  = (const float*)d_in[2];
    const float* Wk  = (const float*)d_in[3];
    const float* bk  = (const float*)d_in[4];
    const float* Wv  = (const float*)d_in[5];
    const float* bv  = (const float*)d_in[6];
    const float* g1  = (const float*)d_in[7];
    const float* be1 = (const float*)d_in[8];
    const float* g2  = (const float*)d_in[9];
    const float* be2 = (const float*)d_in[10];
    const float* W0  = (const float*)d_in[11];
    const float* b0  = (const float*)d_in[12];
    const float* W1  = (const float*)d_in[13];
    const float* b1  = (const float*)d_in[14];

    float* x = (float*)d_out;   // residual stream lives in d_out, fp32 [2048,768]

    char* ws = (char*)d_ws;
    size_t off = 0;
    auto alloc = [&](size_t bytes) -> char* {
        char* p = ws + off; off = (off + bytes + 255) & ~(size_t)255; return p;
    };
    short* wqkvt = (short*)alloc(2304l * 768 * 2);   // [2304,768] = [Wq^T;Wk^T;Wv^T]
    short* w0t   = (short*)alloc(3072l * 768 * 2);   // [3072,768]
    short* w1t   = (short*)alloc(768l * 3072 * 2);   // [768,3072]
    float* bqkv  = (float*)alloc(2304 * 4);
    short* lnb   = (short*)alloc(2048l * 768 * 2);   // LN output (reused)
    short* q     = (short*)alloc(2048l * 768 * 2);   // [B,H,N,64], pre-scaled 1/8
    short* k     = (short*)alloc(2048l * 768 * 2);   // [B,H,N,64]
    short* v     = (short*)alloc(2048l * 768 * 2);   // [B,H,N,64]
    short* vt    = (short*)alloc(2048l * 768 * 2);   // [B,H,64,512]
    short* SP    = (short*)alloc(48l * 512 * 512 * 2); // scores then probs
    short* h     = (short*)alloc(2048l * 3072 * 2);  // FFN hidden

    hipMemcpyAsync(x, x_in, 2048l * 768 * 4, hipMemcpyDeviceToDevice, stream);

    // weight prep (every launch; deterministic, ~26 MB -> negligible)
    transpose_w<<<dim3(24, 24), 256, 0, stream>>>(Wq, wqkvt, 768, 768);
    transpose_w<<<dim3(24, 24), 256, 0, stream>>>(Wk, wqkvt + 768l * 768, 768, 768);
    transpose_w<<<dim3(24, 24), 256, 0, stream>>>(Wv, wqkvt + 2l * 768 * 768, 768, 768);
    transpose_w<<<dim3(96, 24), 256, 0, stream>>>(W0, w0t, 768, 3072);
    transpose_w<<<dim3(24, 96), 256, 0, stream>>>(W1, w1t, 3072, 768);
    concat_bias<<<3, 256, 0, stream>>>(bq, bk, bv, bqkv);

    for (int it = 0; it < 12; ++it) {
        // ln1 -> bf16
        ln_kernel<<<512, 256, 0, stream>>>(x, g1, be1, lnb);
        // QKV projection, scatter to heads (q pre-scaled by 1/8)
        gemm_bt<128, 128, 1><<<dim3(18, 16, 1), 256, 0, stream>>>(
            lnb, wqkvt, bqkv, nullptr, q, k, v, 0, 0, 0, 2048, 2304, 768);
        // V -> V^T per head
        transpose_v<<<dim3(2, 16, 48), 256, 0, stream>>>(v, vt, 512, 64);
        // S = q k^T (48 batches of [512,64]x[64,512])
        gemm_bt<128, 128, 0><<<dim3(4, 4, 48), 256, 0, stream>>>(
            q, k, nullptr, nullptr, SP, nullptr, nullptr,
            512l * 64, 512l * 64, 512l * 512, 512, 512, 64);
        // row softmax in place -> P bf16
        softmax_kernel<<<6144, 256, 0, stream>>>(SP);
        // x += P V  (48 batches of [512,512]x[512,64])
        gemm_bt<128, 64, 4><<<dim3(1, 4, 48), 256, 0, stream>>>(
            SP, vt, nullptr, x, nullptr, nullptr, nullptr,
            512l * 512, 64l * 512, 0, 512, 64, 512);
        // ln2 -> bf16
        ln_kernel<<<512, 256, 0, stream>>>(x, g2, be2, lnb);
        // h = gelu(ln2 @ W0 + b0)
        gemm_bt<128, 128, 2><<<dim3(24, 16, 1), 256, 0, stream>>>(
            lnb, w0t, b0, nullptr, h, nullptr, nullptr, 0, 0, 0, 2048, 3072, 768);
        // x += h @ W1 + b1
        gemm_bt<64, 128, 3><<<dim3(6, 32, 1), 256, 0, stream>>>(
            h, w1t, b1, x, nullptr, nullptr, nullptr, 0, 0, 0, 2048, 768, 3072);
    }
}

// Round 2
// 1442.381 us; speedup vs baseline: 1.1452x; 1.1452x over previous
//
#include <hip/hip_runtime.h>
#include <stdint.h>

// ---------------------------------------------------------------------------
// Types / helpers
// ---------------------------------------------------------------------------
typedef float  f32x4  __attribute__((ext_vector_type(4)));
typedef __bf16 bf16x8 __attribute__((ext_vector_type(8)));
typedef short  s16x8  __attribute__((ext_vector_type(8)));

#define DEV __device__ __forceinline__

DEV short f2b(float f) {  // fp32 -> bf16 bits, round-to-nearest-even
    union { float f; unsigned u; } c; c.f = f;
    unsigned u = c.u;
    unsigned r = (u + 0x7fffu + ((u >> 16) & 1u)) >> 16;
    return (short)r;
}
DEV float b2f(short s) {
    union { unsigned u; float f; } c; c.u = ((unsigned)(unsigned short)s) << 16;
    return c.f;
}

DEV void gload_lds16(const void* g, void* l) {
    // async global->LDS, 16B per lane; LDS dest = wave-uniform base + lane*16
    __builtin_amdgcn_global_load_lds(
        (const __attribute__((address_space(1))) void*)g,
        (__attribute__((address_space(3))) void*)l, 16, 0, 0);
}

// ---------------------------------------------------------------------------
// GEMM: C = A(bf16,[M,K]) * B(bf16, stored as B^T [N,K]) with fused epilogues.
// 2-phase double-buffered pipeline (T3-minimal): STAGE(next) issued BEFORE
// ds_read+MFMA of current; one vmcnt(0)+s_barrier per k-tile.
// LDS XOR-swizzled via pre-swizzled global source; ds_read_b128 conflict-free.
// MODE 0: out bf16 (batched, stride sO)                       [QK^T scores]
// MODE 1: +bias, scatter q(*0.125)/k to [B,H,N,64], v to [B,H,64,N] (V^T)
// MODE 2: +bias, exact GELU, out bf16 row-major                [FFN1]
// MODE 3: +bias(split0), atomicAdd into fp32 out               [FFN2, split-K]
// ---------------------------------------------------------------------------
template<int BM, int BN, int MODE, int NSPLIT>
__global__ __launch_bounds__(256) void gemm_bt(
    const short* __restrict__ A, const short* __restrict__ Bt,
    const float* __restrict__ bias,
    float* __restrict__ outf, short* __restrict__ outs0,
    short* __restrict__ outs1, short* __restrict__ outs2,
    long sA, long sB, long sO, int M, int N, int K)
{
    constexpr int BK = 64;
    constexpr int FM = BM / 32, FN = BN / 32;
    __shared__ __align__(16) short As[2][BM * BK];
    __shared__ __align__(16) short Bs[2][BN * BK];

    const int tid  = threadIdx.x;
    const int w    = tid >> 6, lane = tid & 63;
    const int wr   = w >> 1,  wc   = w & 1;
    const int l16  = lane & 15, lhi = lane >> 4, sw = lane & 7;

    // bijective XCD-aware remap of the (x,y) grid (all grids have nwg%8==0)
    const int gx   = gridDim.x;
    const int nwg  = gx * gridDim.y;
    const int flat = blockIdx.y * gx + blockIdx.x;
    const int nf   = (flat & 7) * (nwg >> 3) + (flat >> 3);
    const int bx   = nf % gx, by = nf / gx;

    int z, kz;
    if constexpr (NSPLIT > 1) { z = 0; kz = blockIdx.z; }
    else                      { z = blockIdx.z; kz = 0; }

    const short* Ab = A  + (long)z * sA + (long)by * BM * K;
    const short* Bb = Bt + (long)z * sB + (long)bx * BN * K;

    const int ktPer = (K >> 6) / NSPLIT;
    const int ktBeg = kz * ktPer, ktEnd = ktBeg + ktPer;

    f32x4 acc[FM][FN];
#pragma unroll
    for (int m = 0; m < FM; ++m)
#pragma unroll
        for (int n = 0; n < FN; ++n) acc[m][n] = (f32x4)(0.0f);

    auto stage = [&](int buf, int kt) {
        const short* Ag = Ab + kt * BK;
#pragma unroll
        for (int i = 0; i < BM / 32; ++i) {
            int seg = i * 256 + tid;
            int row = seg >> 3;
            int gcs = (tid & 7) ^ (row & 7);            // pre-swizzled source
            gload_lds16(Ag + (long)row * K + gcs * 8, &As[buf][(i * 256 + w * 64) * 8]);
        }
        const short* Bg = Bb + kt * BK;
#pragma unroll
        for (int i = 0; i < BN / 32; ++i) {
            int seg = i * 256 + tid;
            int row = seg >> 3;
            int gcs = (tid & 7) ^ (row & 7);
            gload_lds16(Bg + (long)row * K + gcs * 8, &Bs[buf][(i * 256 + w * 64) * 8]);
        }
    };

    stage(0, ktBeg);
    asm volatile("s_waitcnt vmcnt(0)" ::: "memory");
    __builtin_amdgcn_s_barrier();

    int cur = 0;
    for (int kt = ktBeg; kt < ktEnd; ++kt) {
        if (kt + 1 < ktEnd) stage(cur ^ 1, kt + 1);     // prefetch next tile
        const short* Ac = &As[cur][0];
        const short* Bc = &Bs[cur][0];
#pragma unroll
        for (int kk = 0; kk < 2; ++kk) {
            bf16x8 af[FM], bfr[FN];
#pragma unroll
            for (int m = 0; m < FM; ++m) {
                int ar = wr * (BM / 2) + m * 16 + l16;
                int ks = (kk * 4 + lhi) ^ sw;           // ar&7 == sw
                af[m] = *(const bf16x8*)(Ac + ar * BK + ks * 8);
            }
#pragma unroll
            for (int n = 0; n < FN; ++n) {
                int br = wc * (BN / 2) + n * 16 + l16;
                int ks = (kk * 4 + lhi) ^ sw;
                bfr[n] = *(const bf16x8*)(Bc + br * BK + ks * 8);
            }
#pragma unroll
            for (int m = 0; m < FM; ++m)
#pragma unroll
                for (int n = 0; n < FN; ++n)
                    acc[m][n] = __builtin_amdgcn_mfma_f32_16x16x32_bf16(
                        af[m], bfr[n], acc[m][n], 0, 0, 0);
        }
        asm volatile("s_waitcnt vmcnt(0)" ::: "memory");
        __builtin_amdgcn_s_barrier();
        cur ^= 1;
    }

    // Epilogue. C/D frag mapping: col = lane&15, row = (lane>>4)*4 + reg.
    const int m0 = by * BM, n0 = bx * BN;
#pragma unroll
    for (int m = 0; m < FM; ++m) {
#pragma unroll
        for (int n = 0; n < FN; ++n) {
            const int grow0 = m0 + wr * (BM / 2) + m * 16 + lhi * 4;
            const int gcol  = n0 + wc * (BN / 2) + n * 16 + l16;
#pragma unroll
            for (int r = 0; r < 4; ++r) {
                float val = acc[m][n][r];
                int grow = grow0 + r;
                if constexpr (MODE == 0) {
                    outs0[(long)z * sO + (long)grow * N + gcol] = f2b(val);
                } else if constexpr (MODE == 1) {
                    float v = val + bias[gcol];
                    int d  = gcol & 63;
                    int hh = gcol >> 6;                 // 0..35 (uniform per block)
                    int bb = grow >> 9, s = grow & 511;
                    if (hh < 12) {
                        outs0[((long)((bb * 12 + hh) * 512 + s) << 6) + d] = f2b(v * 0.125f);
                    } else if (hh < 24) {
                        outs1[((long)((bb * 12 + (hh - 12)) * 512 + s) << 6) + d] = f2b(v);
                    } else {                             // V stored transposed [B,H,64,512]
                        outs2[((long)((bb * 12 + (hh - 24)) * 64 + d) << 9) + s] = f2b(v);
                    }
                } else if constexpr (MODE == 2) {
                    float v = val + bias[gcol];
                    v = 0.5f * v * (1.0f + erff(v * 0.70710678118f));
                    outs0[(long)grow * N + gcol] = f2b(v);
                } else {                                 // MODE 3: split-K accumulate
                    long idx = (long)grow * N + gcol;
                    float add = val + (kz == 0 ? bias[gcol] : 0.0f);
                    atomicAdd(&outf[idx], add);
                }
            }
        }
    }
}

// ---------------------------------------------------------------------------
// Fused softmax + PV. One block per (q-tile of 64 rows, z=b*12+h).
// Stage P rows (64x512 bf16, granule-swizzled) + V^T tiles (dbuf), softmax
// in-register (f[128] per lane + shfl over 4 lanes), normalize P in LDS,
// then 2-phase MFMA loop. Output: x += P V (exclusive rows/cols, plain +=).
// ---------------------------------------------------------------------------
__global__ __launch_bounds__(256) void attn_pv(
    const short* __restrict__ SP, const short* __restrict__ VT,
    float* __restrict__ x)
{
    __shared__ __align__(16) short P[64 * 512];        // 64 KB
    __shared__ __align__(16) short Vs[2][64 * 64];     // 16 KB

    const int tid = threadIdx.x;
    const int w = tid >> 6, lane = tid & 63;
    const int wr = w >> 1, wc = w & 1;
    const int l16 = lane & 15, lhi = lane >> 4;
    const int z = blockIdx.y;            // 48 = B*H
    const int q0 = blockIdx.x * 64;

    const short* Sg = SP + (long)z * 512 * 512 + (long)q0 * 512;
    const short* Vb = VT + (long)z * 64 * 512;

    auto stageV = [&](int buf, int kt) {
        const short* Vg = Vb + kt * 64;
#pragma unroll
        for (int i = 0; i < 2; ++i) {
            int seg = i * 256 + tid;
            int row = seg >> 3;                          // 0..63 (d-dim)
            int gcs = (tid & 7) ^ (row & 7);
            gload_lds16(Vg + (long)row * 512 + gcs * 8, &Vs[buf][(i * 256 + w * 64) * 8]);
        }
    };

    // stage all P rows: granule-swizzled source, linear LDS dest
#pragma unroll
    for (int i = 0; i < 16; ++i) {
        int seg = i * 256 + tid;
        int row = seg >> 6, g = seg & 63;
        int gs = g ^ (row & 7);
        gload_lds16(Sg + (long)row * 512 + gs * 8, &P[(i * 256 + w * 64) * 8]);
    }
    stageV(0, 0);
    asm volatile("s_waitcnt vmcnt(0)" ::: "memory");
    __syncthreads();

    // --- softmax: lane owns row r = w*16 + l16, quarter lhi of its columns ---
    {
        int r = w * 16 + l16;
        short* Pr = P + r * 512;
        float f[128];
        float mx = -3e38f;
#pragma unroll
        for (int j = 0; j < 16; ++j) {
            int g = lhi * 16 + ((j + l16) & 15);        // bank-spread order
            s16x8 v = *(const s16x8*)(Pr + g * 8);
#pragma unroll
            for (int e = 0; e < 8; ++e) { f[j * 8 + e] = b2f(v[e]); mx = fmaxf(mx, f[j * 8 + e]); }
        }
        mx = fmaxf(mx, __shfl_xor(mx, 16));
        mx = fmaxf(mx, __shfl_xor(mx, 32));
        float sum = 0.f;
#pragma unroll
        for (int i = 0; i < 128; ++i) { f[i] = __expf(f[i] - mx); sum += f[i]; }
        sum += __shfl_xor(sum, 16);
        sum += __shfl_xor(sum, 32);
        float inv = 1.0f / sum;
#pragma unroll
        for (int j = 0; j < 16; ++j) {
            int g = lhi * 16 + ((j + l16) & 15);
            s16x8 o;
#pragma unroll
            for (int e = 0; e < 8; ++e) o[e] = f2b(f[j * 8 + e] * inv);
            *(s16x8*)(Pr + g * 8) = o;
        }
    }
    __syncthreads();

    // --- PV: [64 x 512] x [512 x 64], 2-phase V staging ---
    f32x4 acc[2][2];
#pragma unroll
    for (int m = 0; m < 2; ++m)
#pragma unroll
        for (int n = 0; n < 2; ++n) acc[m][n] = (f32x4)(0.0f);

    int cur = 0;
    for (int kt = 0; kt < 8; ++kt) {
        if (kt < 7) stageV(cur ^ 1, kt + 1);
#pragma unroll
        for (int kk = 0; kk < 2; ++kk) {
            bf16x8 af[2], bfr[2];
#pragma unroll
            for (int m = 0; m < 2; ++m) {
                int ar = wr * 32 + m * 16 + l16;
                int g = kt * 8 + kk * 4 + lhi;          // 64-granule row
                af[m] = *(const bf16x8*)(P + ar * 512 + (g ^ (ar & 7)) * 8);
            }
#pragma unroll
            for (int n = 0; n < 2; ++n) {
                int br = wc * 32 + n * 16 + l16;
                int ks = (kk * 4 + lhi) ^ (br & 7);
                bfr[n] = *(const bf16x8*)(&Vs[cur][br * 64 + ks * 8]);
            }
#pragma unroll
            for (int m = 0; m < 2; ++m)
#pragma unroll
                for (int n = 0; n < 2; ++n)
                    acc[m][n] = __builtin_amdgcn_mfma_f32_16x16x32_bf16(
                        af[m], bfr[n], acc[m][n], 0, 0, 0);
        }
        asm volatile("s_waitcnt vmcnt(0)" ::: "memory");
        __builtin_amdgcn_s_barrier();
        cur ^= 1;
    }

    // x += acc  (rows q0+grow, cols h*64+gcol: exclusive per block)
    const int zb = z / 12, zh = z - (z / 12) * 12;
#pragma unroll
    for (int m = 0; m < 2; ++m) {
#pragma unroll
        for (int n = 0; n < 2; ++n) {
            int grow0 = wr * 32 + m * 16 + lhi * 4;
            int gcol  = wc * 32 + n * 16 + l16;
#pragma unroll
            for (int r = 0; r < 4; ++r) {
                long idx = ((long)(zb * 512 + q0 + grow0 + r)) * 768 + zh * 64 + gcol;
                x[idx] += acc[m][n][r];
            }
        }
    }
}

// ---------------------------------------------------------------------------
// LayerNorm: one wave per row (768 fp32), write bf16
// ---------------------------------------------------------------------------
__global__ __launch_bounds__(256) void ln_kernel(
    const float* __restrict__ x, const float* __restrict__ g,
    const float* __restrict__ be, short* __restrict__ out)
{
    int row  = blockIdx.x * 4 + (threadIdx.x >> 6);
    int lane = threadIdx.x & 63;
    const float4* xr = (const float4*)(x + (long)row * 768);
    float4 v0 = xr[lane], v1 = xr[lane + 64], v2 = xr[lane + 128];
    float f[12] = {v0.x, v0.y, v0.z, v0.w, v1.x, v1.y, v1.z, v1.w, v2.x, v2.y, v2.z, v2.w};

    float s = 0.f;
#pragma unroll
    for (int j = 0; j < 12; ++j) s += f[j];
#pragma unroll
    for (int o = 32; o; o >>= 1) s += __shfl_xor(s, o);
    float mu = s * (1.0f / 768.0f);
    float s2 = 0.f;
#pragma unroll
    for (int j = 0; j < 12; ++j) { f[j] -= mu; s2 += f[j] * f[j]; }
#pragma unroll
    for (int o = 32; o; o >>= 1) s2 += __shfl_xor(s2, o);
    float rstd = rsqrtf(s2 * (1.0f / 768.0f) + 1e-5f);

    const float4* gr = (const float4*)g;
    const float4* br = (const float4*)be;
    short4* orow = (short4*)(out + (long)row * 768);
#pragma unroll
    for (int jb = 0; jb < 3; ++jb) {
        float4 gg = gr[lane + 64 * jb], bb = br[lane + 64 * jb];
        short4 o4;
        o4.x = f2b(f[4 * jb + 0] * rstd * gg.x + bb.x);
        o4.y = f2b(f[4 * jb + 1] * rstd * gg.y + bb.y);
        o4.z = f2b(f[4 * jb + 2] * rstd * gg.z + bb.z);
        o4.w = f2b(f[4 * jb + 3] * rstd * gg.w + bb.w);
        orow[lane + 64 * jb] = o4;
    }
}

// ---------------------------------------------------------------------------
// Weight transpose fp32[R,C] -> bf16[C,R]
// ---------------------------------------------------------------------------
__global__ __launch_bounds__(256) void transpose_w(
    const float* __restrict__ in, short* __restrict__ out, int R, int C)
{
    __shared__ float t[32][33];
    int r0 = blockIdx.y * 32, c0 = blockIdx.x * 32;
    int tx = threadIdx.x & 31, ty = threadIdx.x >> 5;
#pragma unroll
    for (int p = 0; p < 4; ++p)
        t[ty + 8 * p][tx] = in[(long)(r0 + ty + 8 * p) * C + c0 + tx];
    __syncthreads();
#pragma unroll
    for (int p = 0; p < 4; ++p)
        out[(long)(c0 + ty + 8 * p) * R + r0 + tx] = f2b(t[tx][ty + 8 * p]);
}

__global__ void concat_bias(const float* __restrict__ bq, const float* __restrict__ bk,
                            const float* __restrict__ bv, float* __restrict__ o)
{
    int i = blockIdx.x * 256 + threadIdx.x;
    if (i < 768) { o[i] = bq[i]; o[768 + i] = bk[i]; o[1536 + i] = bv[i]; }
}

// ---------------------------------------------------------------------------
// Host launcher
// ---------------------------------------------------------------------------
extern "C" void kernel_launch(void* const* d_in, const int* in_sizes, int n_in,
                              void* d_out, int out_size, void* d_ws, size_t ws_size,
                              hipStream_t stream)
{
    (void)in_sizes; (void)n_in; (void)out_size; (void)ws_size;
    const float* x_in = (const float*)d_in[0];
    const float* Wq  = (const float*)d_in[1];
    const float* bq  = (const float*)d_in[2];
    const float* Wk  = (const float*)d_in[3];
    const float* bk  = (const float*)d_in[4];
    const float* Wv  = (const float*)d_in[5];
    const float* bv  = (const float*)d_in[6];
    const float* g1  = (const float*)d_in[7];
    const float* be1 = (const float*)d_in[8];
    const float* g2  = (const float*)d_in[9];
    const float* be2 = (const float*)d_in[10];
    const float* W0  = (const float*)d_in[11];
    const float* b0  = (const float*)d_in[12];
    const float* W1  = (const float*)d_in[13];
    const float* b1  = (const float*)d_in[14];

    float* x = (float*)d_out;   // residual stream lives in d_out, fp32 [2048,768]

    char* ws = (char*)d_ws;
    size_t off = 0;
    auto alloc = [&](size_t bytes) -> char* {
        char* p = ws + off; off = (off + bytes + 255) & ~(size_t)255; return p;
    };
    short* wqkvt = (short*)alloc(2304l * 768 * 2);   // [Wq^T;Wk^T;Wv^T]
    short* w0t   = (short*)alloc(3072l * 768 * 2);
    short* w1t   = (short*)alloc(768l * 3072 * 2);
    float* bqkv  = (float*)alloc(2304 * 4);
    short* lnb   = (short*)alloc(2048l * 768 * 2);   // LN output
    short* q     = (short*)alloc(2048l * 768 * 2);   // [B,H,512,64], pre-scaled 1/8
    short* k     = (short*)alloc(2048l * 768 * 2);   // [B,H,512,64]
    short* vt    = (short*)alloc(2048l * 768 * 2);   // [B,H,64,512]  (V^T)
    short* SP    = (short*)alloc(48l * 512 * 512 * 2); // scores
    short* h     = (short*)alloc(2048l * 3072 * 2);  // FFN hidden

    hipMemcpyAsync(x, x_in, 2048l * 768 * 4, hipMemcpyDeviceToDevice, stream);

    transpose_w<<<dim3(24, 24), 256, 0, stream>>>(Wq, wqkvt, 768, 768);
    transpose_w<<<dim3(24, 24), 256, 0, stream>>>(Wk, wqkvt + 768l * 768, 768, 768);
    transpose_w<<<dim3(24, 24), 256, 0, stream>>>(Wv, wqkvt + 2l * 768 * 768, 768, 768);
    transpose_w<<<dim3(96, 24), 256, 0, stream>>>(W0, w0t, 768, 3072);
    transpose_w<<<dim3(24, 96), 256, 0, stream>>>(W1, w1t, 3072, 768);
    concat_bias<<<3, 256, 0, stream>>>(bq, bk, bv, bqkv);

    for (int it = 0; it < 12; ++it) {
        ln_kernel<<<512, 256, 0, stream>>>(x, g1, be1, lnb);
        // QKV projection (BN=64 -> 576 blocks), V written transposed
        gemm_bt<128, 64, 1, 1><<<dim3(36, 16, 1), 256, 0, stream>>>(
            lnb, wqkvt, bqkv, nullptr, q, k, vt, 0, 0, 0, 2048, 2304, 768);
        // S = q k^T (48 batches of [512,64]x[64,512])
        gemm_bt<128, 128, 0, 1><<<dim3(4, 4, 48), 256, 0, stream>>>(
            q, k, nullptr, nullptr, SP, nullptr, nullptr,
            512l * 64, 512l * 64, 512l * 512, 512, 512, 64);
        // fused softmax + PV -> x +=
        attn_pv<<<dim3(8, 48), 256, 0, stream>>>(SP, vt, x);
        ln_kernel<<<512, 256, 0, stream>>>(x, g2, be2, lnb);
        // h = gelu(ln2 @ W0 + b0)
        gemm_bt<128, 128, 2, 1><<<dim3(24, 16, 1), 256, 0, stream>>>(
            lnb, w0t, b0, nullptr, h, nullptr, nullptr, 0, 0, 0, 2048, 3072, 768);
        // x += h @ W1 + b1  (split-K=4, atomic accumulate)
        gemm_bt<128, 128, 3, 4><<<dim3(6, 16, 4), 256, 0, stream>>>(
            h, w1t, b1, x, nullptr, nullptr, nullptr, 0, 0, 0, 2048, 768, 3072);
    }
}

// Round 3
// 1323.991 us; speedup vs baseline: 1.2476x; 1.0894x over previous
//
#include <hip/hip_runtime.h>
#include <stdint.h>

// ---------------------------------------------------------------------------
// Types / helpers
// ---------------------------------------------------------------------------
typedef float  f32x4  __attribute__((ext_vector_type(4)));
typedef __bf16 bf16x8 __attribute__((ext_vector_type(8)));
typedef short  s16x8  __attribute__((ext_vector_type(8)));

#define DEV __device__ __forceinline__

DEV short f2b(float f) {  // fp32 -> bf16 bits, round-to-nearest-even
    union { float f; unsigned u; } c; c.f = f;
    unsigned u = c.u;
    unsigned r = (u + 0x7fffu + ((u >> 16) & 1u)) >> 16;
    return (short)r;
}
DEV float b2f(short s) {
    union { unsigned u; float f; } c; c.u = ((unsigned)(unsigned short)s) << 16;
    return c.f;
}

DEV void gload_lds16(const void* g, void* l) {
    // async global->LDS, 16B per lane; LDS dest = wave-uniform base + lane*16
    __builtin_amdgcn_global_load_lds(
        (const __attribute__((address_space(1))) void*)g,
        (__attribute__((address_space(3))) void*)l, 16, 0, 0);
}

// ---------------------------------------------------------------------------
// GEMM: C = A(bf16,[M,K]) * B(bf16, stored as B^T [N,K]) with fused epilogues.
// 2-phase double-buffered pipeline; one vmcnt(0)+s_barrier per k-tile.
// LDS XOR-swizzled via pre-swizzled global source; ds_read_b128 conflict-free.
// MODE 1: +bias, scatter q(*0.125)/k to [B,H,N,64], v to [B,H,64,N] (V^T)
// MODE 2: +bias, exact GELU, out bf16 row-major                [FFN1]
// MODE 3: +bias(split0), atomicAdd into fp32 out               [FFN2, split-K]
// ---------------------------------------------------------------------------
template<int BM, int BN, int MODE, int NSPLIT>
__global__ __launch_bounds__(256) void gemm_bt(
    const short* __restrict__ A, const short* __restrict__ Bt,
    const float* __restrict__ bias,
    float* __restrict__ outf, short* __restrict__ outs0,
    short* __restrict__ outs1, short* __restrict__ outs2,
    long sA, long sB, long sO, int M, int N, int K)
{
    constexpr int BK = 64;
    constexpr int FM = BM / 32, FN = BN / 32;
    __shared__ __align__(16) short As[2][BM * BK];
    __shared__ __align__(16) short Bs[2][BN * BK];

    const int tid  = threadIdx.x;
    const int w    = tid >> 6, lane = tid & 63;
    const int wr   = w >> 1,  wc   = w & 1;
    const int l16  = lane & 15, lhi = lane >> 4, sw = lane & 7;

    // bijective XCD-aware remap of the (x,y) grid (all grids have nwg%8==0)
    const int gx   = gridDim.x;
    const int nwg  = gx * gridDim.y;
    const int flat = blockIdx.y * gx + blockIdx.x;
    const int nf   = (flat & 7) * (nwg >> 3) + (flat >> 3);
    const int bx   = nf % gx, by = nf / gx;

    int z, kz;
    if constexpr (NSPLIT > 1) { z = 0; kz = blockIdx.z; }
    else                      { z = blockIdx.z; kz = 0; }

    const short* Ab = A  + (long)z * sA + (long)by * BM * K;
    const short* Bb = Bt + (long)z * sB + (long)bx * BN * K;

    const int ktPer = (K >> 6) / NSPLIT;
    const int ktBeg = kz * ktPer, ktEnd = ktBeg + ktPer;

    f32x4 acc[FM][FN];
#pragma unroll
    for (int m = 0; m < FM; ++m)
#pragma unroll
        for (int n = 0; n < FN; ++n) acc[m][n] = (f32x4)(0.0f);

    auto stage = [&](int buf, int kt) {
        const short* Ag = Ab + kt * BK;
#pragma unroll
        for (int i = 0; i < BM / 32; ++i) {
            int seg = i * 256 + tid;
            int row = seg >> 3;
            int gcs = (tid & 7) ^ (row & 7);            // pre-swizzled source
            gload_lds16(Ag + (long)row * K + gcs * 8, &As[buf][(i * 256 + w * 64) * 8]);
        }
        const short* Bg = Bb + kt * BK;
#pragma unroll
        for (int i = 0; i < BN / 32; ++i) {
            int seg = i * 256 + tid;
            int row = seg >> 3;
            int gcs = (tid & 7) ^ (row & 7);
            gload_lds16(Bg + (long)row * K + gcs * 8, &Bs[buf][(i * 256 + w * 64) * 8]);
        }
    };

    stage(0, ktBeg);
    asm volatile("s_waitcnt vmcnt(0)" ::: "memory");
    __builtin_amdgcn_s_barrier();

    int cur = 0;
    for (int kt = ktBeg; kt < ktEnd; ++kt) {
        if (kt + 1 < ktEnd) stage(cur ^ 1, kt + 1);     // prefetch next tile
        const short* Ac = &As[cur][0];
        const short* Bc = &Bs[cur][0];
#pragma unroll
        for (int kk = 0; kk < 2; ++kk) {
            bf16x8 af[FM], bfr[FN];
#pragma unroll
            for (int m = 0; m < FM; ++m) {
                int ar = wr * (BM / 2) + m * 16 + l16;
                int ks = (kk * 4 + lhi) ^ sw;           // ar&7 == sw
                af[m] = *(const bf16x8*)(Ac + ar * BK + ks * 8);
            }
#pragma unroll
            for (int n = 0; n < FN; ++n) {
                int br = wc * (BN / 2) + n * 16 + l16;
                int ks = (kk * 4 + lhi) ^ sw;
                bfr[n] = *(const bf16x8*)(Bc + br * BK + ks * 8);
            }
#pragma unroll
            for (int m = 0; m < FM; ++m)
#pragma unroll
                for (int n = 0; n < FN; ++n)
                    acc[m][n] = __builtin_amdgcn_mfma_f32_16x16x32_bf16(
                        af[m], bfr[n], acc[m][n], 0, 0, 0);
        }
        asm volatile("s_waitcnt vmcnt(0)" ::: "memory");
        __builtin_amdgcn_s_barrier();
        cur ^= 1;
    }

    // Epilogue. C/D frag mapping: col = lane&15, row = (lane>>4)*4 + reg.
    const int m0 = by * BM, n0 = bx * BN;
#pragma unroll
    for (int m = 0; m < FM; ++m) {
#pragma unroll
        for (int n = 0; n < FN; ++n) {
            const int grow0 = m0 + wr * (BM / 2) + m * 16 + lhi * 4;
            const int gcol  = n0 + wc * (BN / 2) + n * 16 + l16;
#pragma unroll
            for (int r = 0; r < 4; ++r) {
                float val = acc[m][n][r];
                int grow = grow0 + r;
                if constexpr (MODE == 1) {
                    float v = val + bias[gcol];
                    int d  = gcol & 63;
                    int hh = gcol >> 6;                 // 0..35 (uniform per block)
                    int bb = grow >> 9, s = grow & 511;
                    if (hh < 12) {
                        outs0[((long)((bb * 12 + hh) * 512 + s) << 6) + d] = f2b(v * 0.125f);
                    } else if (hh < 24) {
                        outs1[((long)((bb * 12 + (hh - 12)) * 512 + s) << 6) + d] = f2b(v);
                    } else {                             // V stored transposed [B,H,64,512]
                        outs2[((long)((bb * 12 + (hh - 24)) * 64 + d) << 9) + s] = f2b(v);
                    }
                } else if constexpr (MODE == 2) {
                    float v = val + bias[gcol];
                    v = 0.5f * v * (1.0f + erff(v * 0.70710678118f));
                    outs0[(long)grow * N + gcol] = f2b(v);
                } else {                                 // MODE 3: split-K accumulate
                    long idx = (long)grow * N + gcol;
                    float add = val + (kz == 0 ? bias[gcol] : 0.0f);
                    atomicAdd(&outf[idx], add);
                }
            }
        }
    }
}

// ---------------------------------------------------------------------------
// Fused flash attention: one block per (64-row q-tile, z = b*12+h).
// S never hits global memory. Swapped QK^T (S^T = K·Q^T) so each lane owns a
// k-slice of ONE q-row (q = lane&15) -> online softmax = in-lane reduce +
// 2 shfl_xor. P re-layouts to the PV A-fragment via a small per-wave LDS
// tile (granule-XOR swizzled). K/V tiles double-buffered, 2-phase pipeline.
// Output: x += O (rows/cols exclusive per block -> plain +=).
// ---------------------------------------------------------------------------
__global__ __launch_bounds__(256) void attn_fused(
    const short* __restrict__ Qg,   // [48][512][64] bf16, pre-scaled by 1/8
    const short* __restrict__ Kg,   // [48][512][64]
    const short* __restrict__ VTg,  // [48][64][512]  (V^T per head)
    float* __restrict__ x)          // [2048][768] +=
{
    __shared__ __align__(16) short Qs[64 * 64];        // 8 KB
    __shared__ __align__(16) short Ks[2][64 * 64];     // 16 KB
    __shared__ __align__(16) short Vs[2][64 * 64];     // 16 KB
    __shared__ __align__(16) short Ps[4][16 * 64];     // 8 KB (per-wave P tile)

    const int tid = threadIdx.x;
    const int w = tid >> 6, lane = tid & 63;
    const int l16 = lane & 15, lhi = lane >> 4;

    // XCD grouping: 48 consecutive nf (6 heads) per XCD
    const int f  = blockIdx.y * 8 + blockIdx.x;        // z*8 + qt
    const int nf = (f & 7) * 48 + (f >> 3);
    const int z  = nf >> 3, qt = nf & 7;
    const int q0 = qt * 64;

    const short* Qb = Qg  + (long)z * 512 * 64 + q0 * 64;   // contiguous 64x64
    const short* Kb = Kg  + (long)z * 512 * 64;
    const short* Vb = VTg + (long)z * 64 * 512;

    auto stageQ = [&]() {
#pragma unroll
        for (int i = 0; i < 2; ++i) {
            int seg = i * 256 + tid;
            int row = seg >> 3;
            int gc  = (seg & 7) ^ (row & 7);
            gload_lds16(Qb + row * 64 + gc * 8, Qs + (i * 256 + w * 64) * 8);
        }
    };
    auto stageK = [&](int buf, int kt) {
#pragma unroll
        for (int i = 0; i < 2; ++i) {
            int seg = i * 256 + tid;
            int row = seg >> 3;
            int gc  = (seg & 7) ^ (row & 7);
            gload_lds16(Kb + (kt * 64 + row) * 64 + gc * 8, &Ks[buf][(i * 256 + w * 64) * 8]);
        }
    };
    auto stageV = [&](int buf, int kt) {
#pragma unroll
        for (int i = 0; i < 2; ++i) {
            int seg = i * 256 + tid;
            int row = seg >> 3;                         // d index
            int gc  = (seg & 7) ^ (row & 7);
            gload_lds16(Vb + (long)row * 512 + kt * 64 + gc * 8, &Vs[buf][(i * 256 + w * 64) * 8]);
        }
    };

    stageQ(); stageK(0, 0); stageV(0, 0);
    asm volatile("s_waitcnt vmcnt(0)" ::: "memory");
    __syncthreads();

    // Q b-frags for wave's 16 q-rows (row = w*16 + l16), loaded once
    bf16x8 bq[2];
    {
        int qr = w * 16 + l16;
#pragma unroll
        for (int kk = 0; kk < 2; ++kk)
            bq[kk] = *(const bf16x8*)(Qs + qr * 64 + (((kk * 4 + lhi) ^ (l16 & 7)) * 8));
    }

    float m = -3e38f, l = 0.0f;
    f32x4 acc[4];
#pragma unroll
    for (int bn = 0; bn < 4; ++bn) acc[bn] = (f32x4)(0.0f);

    int cur = 0;
    for (int kt = 0; kt < 8; ++kt) {
        if (kt < 7) { stageK(cur ^ 1, kt + 1); stageV(cur ^ 1, kt + 1); }

        // S^T = K_tile(64 kpos x 64 d) · Q^T : lane holds S[q=l16][k=km*16+lhi*4+r]
        f32x4 s[4];
#pragma unroll
        for (int km = 0; km < 4; ++km) s[km] = (f32x4)(0.0f);
#pragma unroll
        for (int kk = 0; kk < 2; ++kk) {
#pragma unroll
            for (int km = 0; km < 4; ++km) {
                int kr = km * 16 + l16;
                bf16x8 ak = *(const bf16x8*)(&Ks[cur][kr * 64 + (((kk * 4 + lhi) ^ (l16 & 7)) * 8)]);
                s[km] = __builtin_amdgcn_mfma_f32_16x16x32_bf16(ak, bq[kk], s[km], 0, 0, 0);
            }
        }

        // online softmax for q = l16
        float tmax = -3e38f;
#pragma unroll
        for (int km = 0; km < 4; ++km)
#pragma unroll
            for (int r = 0; r < 4; ++r) tmax = fmaxf(tmax, s[km][r]);
        tmax = fmaxf(tmax, __shfl_xor(tmax, 16));
        tmax = fmaxf(tmax, __shfl_xor(tmax, 32));
        float mn = fmaxf(m, tmax);
        float sc = __expf(m - mn);
        float p[16];
        float ts = 0.0f;
#pragma unroll
        for (int km = 0; km < 4; ++km)
#pragma unroll
            for (int r = 0; r < 4; ++r) {
                float e = __expf(s[km][r] - mn);
                p[km * 4 + r] = e; ts += e;
            }
        ts += __shfl_xor(ts, 16);
        ts += __shfl_xor(ts, 32);
        l = l * sc + ts; m = mn;

        // rescale O: acc rows are q = lhi*4+r, sc lives on lane l16==that row
        float scr[4];
#pragma unroll
        for (int r = 0; r < 4; ++r) scr[r] = __shfl(sc, lhi * 4 + r);
#pragma unroll
        for (int bn = 0; bn < 4; ++bn)
#pragma unroll
            for (int r = 0; r < 4; ++r) acc[bn][r] *= scr[r];

        // write P (bf16) to per-wave LDS tile in A-frag layout [q=l16][k]
        {
            short* Pw = &Ps[w][0];
#pragma unroll
            for (int km = 0; km < 4; ++km)
#pragma unroll
                for (int r = 0; r < 4; ++r) {
                    int k = km * 16 + lhi * 4 + r;
                    int g = k >> 3, e = k & 7;
                    Pw[l16 * 64 + ((g ^ (l16 & 7)) * 8) + e] = f2b(p[km * 4 + r]);
                }
        }

        // PV: O(16q x 64d) += P(16q x 64k) · V(64k x 64d)
#pragma unroll
        for (int kk = 0; kk < 2; ++kk) {
            bf16x8 ap = *(const bf16x8*)(&Ps[w][l16 * 64 + (((kk * 4 + lhi) ^ (l16 & 7)) * 8)]);
#pragma unroll
            for (int bn = 0; bn < 4; ++bn) {
                int vr = bn * 16 + l16;
                bf16x8 bv = *(const bf16x8*)(&Vs[cur][vr * 64 + (((kk * 4 + lhi) ^ (l16 & 7)) * 8)]);
                acc[bn] = __builtin_amdgcn_mfma_f32_16x16x32_bf16(ap, bv, acc[bn], 0, 0, 0);
            }
        }

        asm volatile("s_waitcnt vmcnt(0)" ::: "memory");
        __builtin_amdgcn_s_barrier();
        cur ^= 1;
    }

    // epilogue: normalize and accumulate into x
    float inv = 1.0f / l;
    float invr[4];
#pragma unroll
    for (int r = 0; r < 4; ++r) invr[r] = __shfl(inv, lhi * 4 + r);
    const int zb = z / 12, zh = z - (z / 12) * 12;
#pragma unroll
    for (int bn = 0; bn < 4; ++bn)
#pragma unroll
        for (int r = 0; r < 4; ++r) {
            long idx = ((long)(zb * 512 + q0 + w * 16 + lhi * 4 + r)) * 768 + zh * 64 + bn * 16 + l16;
            x[idx] += acc[bn][r] * invr[r];
        }
}

// ---------------------------------------------------------------------------
// LayerNorm: one wave per row (768 fp32), write bf16
// ---------------------------------------------------------------------------
__global__ __launch_bounds__(256) void ln_kernel(
    const float* __restrict__ x, const float* __restrict__ g,
    const float* __restrict__ be, short* __restrict__ out)
{
    int row  = blockIdx.x * 4 + (threadIdx.x >> 6);
    int lane = threadIdx.x & 63;
    const float4* xr = (const float4*)(x + (long)row * 768);
    float4 v0 = xr[lane], v1 = xr[lane + 64], v2 = xr[lane + 128];
    float f[12] = {v0.x, v0.y, v0.z, v0.w, v1.x, v1.y, v1.z, v1.w, v2.x, v2.y, v2.z, v2.w};

    float s = 0.f;
#pragma unroll
    for (int j = 0; j < 12; ++j) s += f[j];
#pragma unroll
    for (int o = 32; o; o >>= 1) s += __shfl_xor(s, o);
    float mu = s * (1.0f / 768.0f);
    float s2 = 0.f;
#pragma unroll
    for (int j = 0; j < 12; ++j) { f[j] -= mu; s2 += f[j] * f[j]; }
#pragma unroll
    for (int o = 32; o; o >>= 1) s2 += __shfl_xor(s2, o);
    float rstd = rsqrtf(s2 * (1.0f / 768.0f) + 1e-5f);

    const float4* gr = (const float4*)g;
    const float4* br = (const float4*)be;
    short4* orow = (short4*)(out + (long)row * 768);
#pragma unroll
    for (int jb = 0; jb < 3; ++jb) {
        float4 gg = gr[lane + 64 * jb], bb = br[lane + 64 * jb];
        short4 o4;
        o4.x = f2b(f[4 * jb + 0] * rstd * gg.x + bb.x);
        o4.y = f2b(f[4 * jb + 1] * rstd * gg.y + bb.y);
        o4.z = f2b(f[4 * jb + 2] * rstd * gg.z + bb.z);
        o4.w = f2b(f[4 * jb + 3] * rstd * gg.w + bb.w);
        orow[lane + 64 * jb] = o4;
    }
}

// ---------------------------------------------------------------------------
// Weight transpose fp32[R,C] -> bf16[C,R]
// ---------------------------------------------------------------------------
__global__ __launch_bounds__(256) void transpose_w(
    const float* __restrict__ in, short* __restrict__ out, int R, int C)
{
    __shared__ float t[32][33];
    int r0 = blockIdx.y * 32, c0 = blockIdx.x * 32;
    int tx = threadIdx.x & 31, ty = threadIdx.x >> 5;
#pragma unroll
    for (int p = 0; p < 4; ++p)
        t[ty + 8 * p][tx] = in[(long)(r0 + ty + 8 * p) * C + c0 + tx];
    __syncthreads();
#pragma unroll
    for (int p = 0; p < 4; ++p)
        out[(long)(c0 + ty + 8 * p) * R + r0 + tx] = f2b(t[tx][ty + 8 * p]);
}

__global__ void concat_bias(const float* __restrict__ bq, const float* __restrict__ bk,
                            const float* __restrict__ bv, float* __restrict__ o)
{
    int i = blockIdx.x * 256 + threadIdx.x;
    if (i < 768) { o[i] = bq[i]; o[768 + i] = bk[i]; o[1536 + i] = bv[i]; }
}

// ---------------------------------------------------------------------------
// Host launcher
// ---------------------------------------------------------------------------
extern "C" void kernel_launch(void* const* d_in, const int* in_sizes, int n_in,
                              void* d_out, int out_size, void* d_ws, size_t ws_size,
                              hipStream_t stream)
{
    (void)in_sizes; (void)n_in; (void)out_size; (void)ws_size;
    const float* x_in = (const float*)d_in[0];
    const float* Wq  = (const float*)d_in[1];
    const float* bq  = (const float*)d_in[2];
    const float* Wk  = (const float*)d_in[3];
    const float* bk  = (const float*)d_in[4];
    const float* Wv  = (const float*)d_in[5];
    const float* bv  = (const float*)d_in[6];
    const float* g1  = (const float*)d_in[7];
    const float* be1 = (const float*)d_in[8];
    const float* g2  = (const float*)d_in[9];
    const float* be2 = (const float*)d_in[10];
    const float* W0  = (const float*)d_in[11];
    const float* b0  = (const float*)d_in[12];
    const float* W1  = (const float*)d_in[13];
    const float* b1  = (const float*)d_in[14];

    float* x = (float*)d_out;   // residual stream lives in d_out, fp32 [2048,768]

    char* ws = (char*)d_ws;
    size_t off = 0;
    auto alloc = [&](size_t bytes) -> char* {
        char* p = ws + off; off = (off + bytes + 255) & ~(size_t)255; return p;
    };
    short* wqkvt = (short*)alloc(2304l * 768 * 2);   // [Wq^T;Wk^T;Wv^T]
    short* w0t   = (short*)alloc(3072l * 768 * 2);
    short* w1t   = (short*)alloc(768l * 3072 * 2);
    float* bqkv  = (float*)alloc(2304 * 4);
    short* lnb   = (short*)alloc(2048l * 768 * 2);   // LN output
    short* q     = (short*)alloc(2048l * 768 * 2);   // [B,H,512,64], pre-scaled 1/8
    short* k     = (short*)alloc(2048l * 768 * 2);   // [B,H,512,64]
    short* vt    = (short*)alloc(2048l * 768 * 2);   // [B,H,64,512]  (V^T)
    short* h     = (short*)alloc(2048l * 3072 * 2);  // FFN hidden

    hipMemcpyAsync(x, x_in, 2048l * 768 * 4, hipMemcpyDeviceToDevice, stream);

    transpose_w<<<dim3(24, 24), 256, 0, stream>>>(Wq, wqkvt, 768, 768);
    transpose_w<<<dim3(24, 24), 256, 0, stream>>>(Wk, wqkvt + 768l * 768, 768, 768);
    transpose_w<<<dim3(24, 24), 256, 0, stream>>>(Wv, wqkvt + 2l * 768 * 768, 768, 768);
    transpose_w<<<dim3(96, 24), 256, 0, stream>>>(W0, w0t, 768, 3072);
    transpose_w<<<dim3(24, 96), 256, 0, stream>>>(W1, w1t, 3072, 768);
    concat_bias<<<3, 256, 0, stream>>>(bq, bk, bv, bqkv);

    for (int it = 0; it < 12; ++it) {
        ln_kernel<<<512, 256, 0, stream>>>(x, g1, be1, lnb);
        // QKV projection (BN=64 -> 576 blocks), V written transposed
        gemm_bt<128, 64, 1, 1><<<dim3(36, 16, 1), 256, 0, stream>>>(
            lnb, wqkvt, bqkv, nullptr, q, k, vt, 0, 0, 0, 2048, 2304, 768);
        // fused flash attention: x += softmax(q k^T) v
        attn_fused<<<dim3(8, 48), 256, 0, stream>>>(q, k, vt, x);
        ln_kernel<<<512, 256, 0, stream>>>(x, g2, be2, lnb);
        // h = gelu(ln2 @ W0 + b0)
        gemm_bt<128, 128, 2, 1><<<dim3(24, 16, 1), 256, 0, stream>>>(
            lnb, w0t, b0, nullptr, h, nullptr, nullptr, 0, 0, 0, 2048, 3072, 768);
        // x += h @ W1 + b1  (split-K=4, atomic accumulate)
        gemm_bt<128, 128, 3, 4><<<dim3(6, 16, 4), 256, 0, stream>>>(
            h, w1t, b1, x, nullptr, nullptr, nullptr, 0, 0, 0, 2048, 768, 3072);
    }
}

// Round 4
// 1160.145 us; speedup vs baseline: 1.4238x; 1.1412x over previous
//
#include <hip/hip_runtime.h>
#include <stdint.h>

// ---------------------------------------------------------------------------
// Types / helpers
// ---------------------------------------------------------------------------
typedef float  f32x4  __attribute__((ext_vector_type(4)));
typedef __bf16 bf16x8 __attribute__((ext_vector_type(8)));
typedef short  s16x8  __attribute__((ext_vector_type(8)));

#define DEV __device__ __forceinline__

DEV short f2b(float f) {  // fp32 -> bf16 bits, round-to-nearest-even
    union { float f; unsigned u; } c; c.f = f;
    unsigned u = c.u;
    unsigned r = (u + 0x7fffu + ((u >> 16) & 1u)) >> 16;
    return (short)r;
}
DEV float b2f(short s) {
    union { unsigned u; float f; } c; c.u = ((unsigned)(unsigned short)s) << 16;
    return c.f;
}

DEV void gload_lds16(const void* g, void* l) {
    // async global->LDS, 16B per lane; LDS dest = wave-uniform base + lane*16
    __builtin_amdgcn_global_load_lds(
        (const __attribute__((address_space(1))) void*)g,
        (__attribute__((address_space(3))) void*)l, 16, 0, 0);
}

// ---------------------------------------------------------------------------
// GEMM: C = A(bf16,[M,K]) * B(bf16, stored as B^T [N,K]) with fused epilogues.
// 64x64 tiles (32 KB LDS dbuf -> 5 blocks/CU for TLP), 2-phase pipeline,
// one vmcnt(0)+s_barrier per k-tile. LDS XOR-swizzled via pre-swizzled
// global source; ds_read_b128 conflict-free.
// MODE 1: +bias, scatter q(*0.125)/k to [B,H,N,64], v to [B,H,64,N] (V^T)
// MODE 2: +bias, exact GELU, out bf16 row-major                [FFN1]
// MODE 3: fp32 partial store per split (no bias)               [FFN2 split-K]
// ---------------------------------------------------------------------------
template<int BM, int BN, int MODE, int NSPLIT>
__global__ __launch_bounds__(256) void gemm_bt(
    const short* __restrict__ A, const short* __restrict__ Bt,
    const float* __restrict__ bias,
    float* __restrict__ outf, short* __restrict__ outs0,
    short* __restrict__ outs1, short* __restrict__ outs2,
    long sA, long sB, long sO, int M, int N, int K)
{
    constexpr int BK = 64;
    constexpr int FM = BM / 32, FN = BN / 32;
    __shared__ __align__(16) short As[2][BM * BK];
    __shared__ __align__(16) short Bs[2][BN * BK];

    const int tid  = threadIdx.x;
    const int w    = tid >> 6, lane = tid & 63;
    const int wr   = w >> 1,  wc   = w & 1;
    const int l16  = lane & 15, lhi = lane >> 4, sw = lane & 7;

    // bijective XCD-aware remap of the (x,y) grid (all grids have nwg%8==0)
    const int gx   = gridDim.x;
    const int nwg  = gx * gridDim.y;
    const int flat = blockIdx.y * gx + blockIdx.x;
    const int nf   = (flat & 7) * (nwg >> 3) + (flat >> 3);
    const int bx   = nf % gx, by = nf / gx;

    int z, kz;
    if constexpr (NSPLIT > 1) { z = 0; kz = blockIdx.z; }
    else                      { z = blockIdx.z; kz = 0; }

    const short* Ab = A  + (long)z * sA + (long)by * BM * K;
    const short* Bb = Bt + (long)z * sB + (long)bx * BN * K;

    const int ktPer = (K >> 6) / NSPLIT;
    const int ktBeg = kz * ktPer, ktEnd = ktBeg + ktPer;

    f32x4 acc[FM][FN];
#pragma unroll
    for (int m = 0; m < FM; ++m)
#pragma unroll
        for (int n = 0; n < FN; ++n) acc[m][n] = (f32x4)(0.0f);

    auto stage = [&](int buf, int kt) {
        const short* Ag = Ab + kt * BK;
#pragma unroll
        for (int i = 0; i < BM / 32; ++i) {
            int seg = i * 256 + tid;
            int row = seg >> 3;
            int gcs = (tid & 7) ^ (row & 7);            // pre-swizzled source
            gload_lds16(Ag + (long)row * K + gcs * 8, &As[buf][(i * 256 + w * 64) * 8]);
        }
        const short* Bg = Bb + kt * BK;
#pragma unroll
        for (int i = 0; i < BN / 32; ++i) {
            int seg = i * 256 + tid;
            int row = seg >> 3;
            int gcs = (tid & 7) ^ (row & 7);
            gload_lds16(Bg + (long)row * K + gcs * 8, &Bs[buf][(i * 256 + w * 64) * 8]);
        }
    };

    stage(0, ktBeg);
    asm volatile("s_waitcnt vmcnt(0)" ::: "memory");
    __builtin_amdgcn_s_barrier();

    int cur = 0;
    for (int kt = ktBeg; kt < ktEnd; ++kt) {
        if (kt + 1 < ktEnd) stage(cur ^ 1, kt + 1);     // prefetch next tile
        const short* Ac = &As[cur][0];
        const short* Bc = &Bs[cur][0];
#pragma unroll
        for (int kk = 0; kk < 2; ++kk) {
            bf16x8 af[FM], bfr[FN];
#pragma unroll
            for (int m = 0; m < FM; ++m) {
                int ar = wr * (BM / 2) + m * 16 + l16;
                int ks = (kk * 4 + lhi) ^ sw;           // ar&7 == sw
                af[m] = *(const bf16x8*)(Ac + ar * BK + ks * 8);
            }
#pragma unroll
            for (int n = 0; n < FN; ++n) {
                int br = wc * (BN / 2) + n * 16 + l16;
                int ks = (kk * 4 + lhi) ^ sw;
                bfr[n] = *(const bf16x8*)(Bc + br * BK + ks * 8);
            }
#pragma unroll
            for (int m = 0; m < FM; ++m)
#pragma unroll
                for (int n = 0; n < FN; ++n)
                    acc[m][n] = __builtin_amdgcn_mfma_f32_16x16x32_bf16(
                        af[m], bfr[n], acc[m][n], 0, 0, 0);
        }
        asm volatile("s_waitcnt vmcnt(0)" ::: "memory");
        __builtin_amdgcn_s_barrier();
        cur ^= 1;
    }

    // Epilogue. C/D frag mapping: col = lane&15, row = (lane>>4)*4 + reg.
    const int m0 = by * BM, n0 = bx * BN;
#pragma unroll
    for (int m = 0; m < FM; ++m) {
#pragma unroll
        for (int n = 0; n < FN; ++n) {
            const int grow0 = m0 + wr * (BM / 2) + m * 16 + lhi * 4;
            const int gcol  = n0 + wc * (BN / 2) + n * 16 + l16;
#pragma unroll
            for (int r = 0; r < 4; ++r) {
                float val = acc[m][n][r];
                int grow = grow0 + r;
                if constexpr (MODE == 1) {
                    float v = val + bias[gcol];
                    int d  = gcol & 63;
                    int hh = gcol >> 6;                 // 0..35 (uniform per block)
                    int bb = grow >> 9, s = grow & 511;
                    if (hh < 12) {
                        outs0[((long)((bb * 12 + hh) * 512 + s) << 6) + d] = f2b(v * 0.125f);
                    } else if (hh < 24) {
                        outs1[((long)((bb * 12 + (hh - 12)) * 512 + s) << 6) + d] = f2b(v);
                    } else {                             // V stored transposed [B,H,64,512]
                        outs2[((long)((bb * 12 + (hh - 24)) * 64 + d) << 9) + s] = f2b(v);
                    }
                } else if constexpr (MODE == 2) {
                    float v = val + bias[gcol];
                    v = 0.5f * v * (1.0f + erff(v * 0.70710678118f));
                    outs0[(long)grow * N + gcol] = f2b(v);
                } else {                                 // MODE 3: fp32 partial store
                    outf[(long)kz * M * N + (long)grow * N + gcol] = val;
                }
            }
        }
    }
}

// ---------------------------------------------------------------------------
// FFN2 split-K reduce: x += p0 + p1 + b1   (float4 vectorized)
// ---------------------------------------------------------------------------
__global__ __launch_bounds__(256) void ffn2_reduce(
    const float* __restrict__ part, const float* __restrict__ bias,
    float* __restrict__ x)
{
    int i4 = blockIdx.x * 256 + threadIdx.x;            // over 2048*768/4
    const float4* p0 = (const float4*)part;
    const float4* p1 = (const float4*)(part + 2048l * 768);
    const float4* b4 = (const float4*)bias;
    float4* x4 = (float4*)x;
    float4 a = p0[i4], b = p1[i4], bb = b4[i4 % 192], xv = x4[i4];
    xv.x += a.x + b.x + bb.x;
    xv.y += a.y + b.y + bb.y;
    xv.z += a.z + b.z + bb.z;
    xv.w += a.w + b.w + bb.w;
    x4[i4] = xv;
}

// ---------------------------------------------------------------------------
// Fused flash attention: one block per (64-row q-tile, z = b*12+h).
// Swapped QK^T (S^T = K·Q^T) so each lane owns a k-slice of ONE q-row
// (q = lane&15) -> online softmax = in-lane reduce + 2 shfl_xor. P re-layouts
// to the PV A-fragment via a per-wave LDS tile. K/V dbuf, 2-phase pipeline.
// Output: x += O (rows/cols exclusive per block -> plain +=).
// ---------------------------------------------------------------------------
__global__ __launch_bounds__(256) void attn_fused(
    const short* __restrict__ Qg,   // [48][512][64] bf16, pre-scaled by 1/8
    const short* __restrict__ Kg,   // [48][512][64]
    const short* __restrict__ VTg,  // [48][64][512]  (V^T per head)
    float* __restrict__ x)          // [2048][768] +=
{
    __shared__ __align__(16) short Qs[64 * 64];        // 8 KB
    __shared__ __align__(16) short Ks[2][64 * 64];     // 16 KB
    __shared__ __align__(16) short Vs[2][64 * 64];     // 16 KB
    __shared__ __align__(16) short Ps[4][16 * 64];     // 8 KB (per-wave P tile)

    const int tid = threadIdx.x;
    const int w = tid >> 6, lane = tid & 63;
    const int l16 = lane & 15, lhi = lane >> 4;

    // XCD grouping: 48 consecutive nf (6 heads) per XCD
    const int f  = blockIdx.y * 8 + blockIdx.x;        // z*8 + qt
    const int nf = (f & 7) * 48 + (f >> 3);
    const int z  = nf >> 3, qt = nf & 7;
    const int q0 = qt * 64;

    const short* Qb = Qg  + (long)z * 512 * 64 + q0 * 64;   // contiguous 64x64
    const short* Kb = Kg  + (long)z * 512 * 64;
    const short* Vb = VTg + (long)z * 64 * 512;

    auto stageQ = [&]() {
#pragma unroll
        for (int i = 0; i < 2; ++i) {
            int seg = i * 256 + tid;
            int row = seg >> 3;
            int gc  = (seg & 7) ^ (row & 7);
            gload_lds16(Qb + row * 64 + gc * 8, Qs + (i * 256 + w * 64) * 8);
        }
    };
    auto stageK = [&](int buf, int kt) {
#pragma unroll
        for (int i = 0; i < 2; ++i) {
            int seg = i * 256 + tid;
            int row = seg >> 3;
            int gc  = (seg & 7) ^ (row & 7);
            gload_lds16(Kb + (kt * 64 + row) * 64 + gc * 8, &Ks[buf][(i * 256 + w * 64) * 8]);
        }
    };
    auto stageV = [&](int buf, int kt) {
#pragma unroll
        for (int i = 0; i < 2; ++i) {
            int seg = i * 256 + tid;
            int row = seg >> 3;                         // d index
            int gc  = (seg & 7) ^ (row & 7);
            gload_lds16(Vb + (long)row * 512 + kt * 64 + gc * 8, &Vs[buf][(i * 256 + w * 64) * 8]);
        }
    };

    stageQ(); stageK(0, 0); stageV(0, 0);
    asm volatile("s_waitcnt vmcnt(0)" ::: "memory");
    __syncthreads();

    // Q b-frags for wave's 16 q-rows (row = w*16 + l16), loaded once
    bf16x8 bq[2];
    {
        int qr = w * 16 + l16;
#pragma unroll
        for (int kk = 0; kk < 2; ++kk)
            bq[kk] = *(const bf16x8*)(Qs + qr * 64 + (((kk * 4 + lhi) ^ (l16 & 7)) * 8));
    }

    float m = -3e38f, l = 0.0f;
    f32x4 acc[4];
#pragma unroll
    for (int bn = 0; bn < 4; ++bn) acc[bn] = (f32x4)(0.0f);

    int cur = 0;
    for (int kt = 0; kt < 8; ++kt) {
        if (kt < 7) { stageK(cur ^ 1, kt + 1); stageV(cur ^ 1, kt + 1); }

        // S^T = K_tile(64 kpos x 64 d) · Q^T : lane holds S[q=l16][k=km*16+lhi*4+r]
        f32x4 s[4];
#pragma unroll
        for (int km = 0; km < 4; ++km) s[km] = (f32x4)(0.0f);
#pragma unroll
        for (int kk = 0; kk < 2; ++kk) {
#pragma unroll
            for (int km = 0; km < 4; ++km) {
                int kr = km * 16 + l16;
                bf16x8 ak = *(const bf16x8*)(&Ks[cur][kr * 64 + (((kk * 4 + lhi) ^ (l16 & 7)) * 8)]);
                s[km] = __builtin_amdgcn_mfma_f32_16x16x32_bf16(ak, bq[kk], s[km], 0, 0, 0);
            }
        }

        // online softmax for q = l16
        float tmax = -3e38f;
#pragma unroll
        for (int km = 0; km < 4; ++km)
#pragma unroll
            for (int r = 0; r < 4; ++r) tmax = fmaxf(tmax, s[km][r]);
        tmax = fmaxf(tmax, __shfl_xor(tmax, 16));
        tmax = fmaxf(tmax, __shfl_xor(tmax, 32));
        float mn = fmaxf(m, tmax);
        float sc = __expf(m - mn);
        float p[16];
        float ts = 0.0f;
#pragma unroll
        for (int km = 0; km < 4; ++km)
#pragma unroll
            for (int r = 0; r < 4; ++r) {
                float e = __expf(s[km][r] - mn);
                p[km * 4 + r] = e; ts += e;
            }
        ts += __shfl_xor(ts, 16);
        ts += __shfl_xor(ts, 32);
        l = l * sc + ts; m = mn;

        // rescale O: acc rows are q = lhi*4+r, sc lives on lane l16==that row
        float scr[4];
#pragma unroll
        for (int r = 0; r < 4; ++r) scr[r] = __shfl(sc, lhi * 4 + r);
#pragma unroll
        for (int bn = 0; bn < 4; ++bn)
#pragma unroll
            for (int r = 0; r < 4; ++r) acc[bn][r] *= scr[r];

        // write P (bf16) to per-wave LDS tile in A-frag layout [q=l16][k]
        {
            short* Pw = &Ps[w][0];
#pragma unroll
            for (int km = 0; km < 4; ++km)
#pragma unroll
                for (int r = 0; r < 4; ++r) {
                    int k = km * 16 + lhi * 4 + r;
                    int g = k >> 3, e = k & 7;
                    Pw[l16 * 64 + ((g ^ (l16 & 7)) * 8) + e] = f2b(p[km * 4 + r]);
                }
        }

        // PV: O(16q x 64d) += P(16q x 64k) · V(64k x 64d)
#pragma unroll
        for (int kk = 0; kk < 2; ++kk) {
            bf16x8 ap = *(const bf16x8*)(&Ps[w][l16 * 64 + (((kk * 4 + lhi) ^ (l16 & 7)) * 8)]);
#pragma unroll
            for (int bn = 0; bn < 4; ++bn) {
                int vr = bn * 16 + l16;
                bf16x8 bv = *(const bf16x8*)(&Vs[cur][vr * 64 + (((kk * 4 + lhi) ^ (l16 & 7)) * 8)]);
                acc[bn] = __builtin_amdgcn_mfma_f32_16x16x32_bf16(ap, bv, acc[bn], 0, 0, 0);
            }
        }

        asm volatile("s_waitcnt vmcnt(0)" ::: "memory");
        __builtin_amdgcn_s_barrier();
        cur ^= 1;
    }

    // epilogue: normalize and accumulate into x
    float inv = 1.0f / l;
    float invr[4];
#pragma unroll
    for (int r = 0; r < 4; ++r) invr[r] = __shfl(inv, lhi * 4 + r);
    const int zb = z / 12, zh = z - (z / 12) * 12;
#pragma unroll
    for (int bn = 0; bn < 4; ++bn)
#pragma unroll
        for (int r = 0; r < 4; ++r) {
            long idx = ((long)(zb * 512 + q0 + w * 16 + lhi * 4 + r)) * 768 + zh * 64 + bn * 16 + l16;
            x[idx] += acc[bn][r] * invr[r];
        }
}

// ---------------------------------------------------------------------------
// LayerNorm: one wave per row (768 fp32), write bf16
// ---------------------------------------------------------------------------
__global__ __launch_bounds__(256) void ln_kernel(
    const float* __restrict__ x, const float* __restrict__ g,
    const float* __restrict__ be, short* __restrict__ out)
{
    int row  = blockIdx.x * 4 + (threadIdx.x >> 6);
    int lane = threadIdx.x & 63;
    const float4* xr = (const float4*)(x + (long)row * 768);
    float4 v0 = xr[lane], v1 = xr[lane + 64], v2 = xr[lane + 128];
    float f[12] = {v0.x, v0.y, v0.z, v0.w, v1.x, v1.y, v1.z, v1.w, v2.x, v2.y, v2.z, v2.w};

    float s = 0.f;
#pragma unroll
    for (int j = 0; j < 12; ++j) s += f[j];
#pragma unroll
    for (int o = 32; o; o >>= 1) s += __shfl_xor(s, o);
    float mu = s * (1.0f / 768.0f);
    float s2 = 0.f;
#pragma unroll
    for (int j = 0; j < 12; ++j) { f[j] -= mu; s2 += f[j] * f[j]; }
#pragma unroll
    for (int o = 32; o; o >>= 1) s2 += __shfl_xor(s2, o);
    float rstd = rsqrtf(s2 * (1.0f / 768.0f) + 1e-5f);

    const float4* gr = (const float4*)g;
    const float4* br = (const float4*)be;
    short4* orow = (short4*)(out + (long)row * 768);
#pragma unroll
    for (int jb = 0; jb < 3; ++jb) {
        float4 gg = gr[lane + 64 * jb], bb = br[lane + 64 * jb];
        short4 o4;
        o4.x = f2b(f[4 * jb + 0] * rstd * gg.x + bb.x);
        o4.y = f2b(f[4 * jb + 1] * rstd * gg.y + bb.y);
        o4.z = f2b(f[4 * jb + 2] * rstd * gg.z + bb.z);
        o4.w = f2b(f[4 * jb + 3] * rstd * gg.w + bb.w);
        orow[lane + 64 * jb] = o4;
    }
}

// ---------------------------------------------------------------------------
// Weight transpose fp32[R,C] -> bf16[C,R]
// ---------------------------------------------------------------------------
__global__ __launch_bounds__(256) void transpose_w(
    const float* __restrict__ in, short* __restrict__ out, int R, int C)
{
    __shared__ float t[32][33];
    int r0 = blockIdx.y * 32, c0 = blockIdx.x * 32;
    int tx = threadIdx.x & 31, ty = threadIdx.x >> 5;
#pragma unroll
    for (int p = 0; p < 4; ++p)
        t[ty + 8 * p][tx] = in[(long)(r0 + ty + 8 * p) * C + c0 + tx];
    __syncthreads();
#pragma unroll
    for (int p = 0; p < 4; ++p)
        out[(long)(c0 + ty + 8 * p) * R + r0 + tx] = f2b(t[tx][ty + 8 * p]);
}

__global__ void concat_bias(const float* __restrict__ bq, const float* __restrict__ bk,
                            const float* __restrict__ bv, float* __restrict__ o)
{
    int i = blockIdx.x * 256 + threadIdx.x;
    if (i < 768) { o[i] = bq[i]; o[768 + i] = bk[i]; o[1536 + i] = bv[i]; }
}

// ---------------------------------------------------------------------------
// Host launcher
// ---------------------------------------------------------------------------
extern "C" void kernel_launch(void* const* d_in, const int* in_sizes, int n_in,
                              void* d_out, int out_size, void* d_ws, size_t ws_size,
                              hipStream_t stream)
{
    (void)in_sizes; (void)n_in; (void)out_size; (void)ws_size;
    const float* x_in = (const float*)d_in[0];
    const float* Wq  = (const float*)d_in[1];
    const float* bq  = (const float*)d_in[2];
    const float* Wk  = (const float*)d_in[3];
    const float* bk  = (const float*)d_in[4];
    const float* Wv  = (const float*)d_in[5];
    const float* bv  = (const float*)d_in[6];
    const float* g1  = (const float*)d_in[7];
    const float* be1 = (const float*)d_in[8];
    const float* g2  = (const float*)d_in[9];
    const float* be2 = (const float*)d_in[10];
    const float* W0  = (const float*)d_in[11];
    const float* b0  = (const float*)d_in[12];
    const float* W1  = (const float*)d_in[13];
    const float* b1  = (const float*)d_in[14];

    float* x = (float*)d_out;   // residual stream lives in d_out, fp32 [2048,768]

    char* ws = (char*)d_ws;
    size_t off = 0;
    auto alloc = [&](size_t bytes) -> char* {
        char* p = ws + off; off = (off + bytes + 255) & ~(size_t)255; return p;
    };
    short* wqkvt = (short*)alloc(2304l * 768 * 2);   // [Wq^T;Wk^T;Wv^T]
    short* w0t   = (short*)alloc(3072l * 768 * 2);
    short* w1t   = (short*)alloc(768l * 3072 * 2);
    float* bqkv  = (float*)alloc(2304 * 4);
    short* lnb   = (short*)alloc(2048l * 768 * 2);   // LN output
    short* q     = (short*)alloc(2048l * 768 * 2);   // [B,H,512,64], pre-scaled 1/8
    short* k     = (short*)alloc(2048l * 768 * 2);   // [B,H,512,64]
    short* vt    = (short*)alloc(2048l * 768 * 2);   // [B,H,64,512]  (V^T)
    short* h     = (short*)alloc(2048l * 3072 * 2);  // FFN hidden
    float* part  = (float*)alloc(2l * 2048 * 768 * 4); // FFN2 split-K partials

    hipMemcpyAsync(x, x_in, 2048l * 768 * 4, hipMemcpyDeviceToDevice, stream);

    transpose_w<<<dim3(24, 24), 256, 0, stream>>>(Wq, wqkvt, 768, 768);
    transpose_w<<<dim3(24, 24), 256, 0, stream>>>(Wk, wqkvt + 768l * 768, 768, 768);
    transpose_w<<<dim3(24, 24), 256, 0, stream>>>(Wv, wqkvt + 2l * 768 * 768, 768, 768);
    transpose_w<<<dim3(96, 24), 256, 0, stream>>>(W0, w0t, 768, 3072);
    transpose_w<<<dim3(24, 96), 256, 0, stream>>>(W1, w1t, 3072, 768);
    concat_bias<<<3, 256, 0, stream>>>(bq, bk, bv, bqkv);

    for (int it = 0; it < 12; ++it) {
        ln_kernel<<<512, 256, 0, stream>>>(x, g1, be1, lnb);
        // QKV projection: 64x64 tiles, 1152 blocks, V written transposed
        gemm_bt<64, 64, 1, 1><<<dim3(36, 32, 1), 256, 0, stream>>>(
            lnb, wqkvt, bqkv, nullptr, q, k, vt, 0, 0, 0, 2048, 2304, 768);
        // fused flash attention: x += softmax(q k^T) v
        attn_fused<<<dim3(8, 48), 256, 0, stream>>>(q, k, vt, x);
        ln_kernel<<<512, 256, 0, stream>>>(x, g2, be2, lnb);
        // h = gelu(ln2 @ W0 + b0): 64x64 tiles, 1536 blocks
        gemm_bt<64, 64, 2, 1><<<dim3(48, 32, 1), 256, 0, stream>>>(
            lnb, w0t, b0, nullptr, h, nullptr, nullptr, 0, 0, 0, 2048, 3072, 768);
        // FFN2: split-K=2 fp32 partials (no atomics), 768 blocks
        gemm_bt<64, 64, 3, 2><<<dim3(12, 32, 2), 256, 0, stream>>>(
            h, w1t, nullptr, part, nullptr, nullptr, nullptr, 0, 0, 0, 2048, 768, 3072);
        // x += p0 + p1 + b1
        ffn2_reduce<<<1536, 256, 0, stream>>>(part, b1, x);
    }
}